// Round 7
// baseline (708.366 us; speedup 1.0000x reference)
//
#include <hip/hip_runtime.h>

#define EPS 1e-5f
#define KK 27

typedef __bf16 bf16x8 __attribute__((ext_vector_type(8)));
typedef float f32x4 __attribute__((ext_vector_type(4)));

__device__ __forceinline__ unsigned short f2bf(float f) {
    union { float f; unsigned u; } v; v.f = f;
    unsigned r = v.u + 0x7fffu + ((v.u >> 16) & 1u);  // round-to-nearest-even
    return (unsigned short)(r >> 16);
}
__device__ __forceinline__ float bf2f(unsigned short h) {
    union { unsigned u; float f; } v; v.u = ((unsigned)h) << 16; return v.f;
}

__device__ __forceinline__ f32x4 mfma16(bf16x8 a, bf16x8 b, f32x4 c) {
    return __builtin_amdgcn_mfma_f32_16x16x32_bf16(a, b, c, 0, 0, 0);
}

// s_waitcnt vmcnt(0), exp/lgkm untouched (gfx9 encoding)
__device__ __forceinline__ void wait_vm0() { __builtin_amdgcn_s_waitcnt(0xF70); }

__device__ __forceinline__ void gatherA(const unsigned short* __restrict__ xin,
                                        int i0, int i1, int quad, bf16x8 (&dst)[2][2]) {
    const unsigned short* r0 = xin + (long)i0 * 64 + quad * 8;
    const unsigned short* r1 = xin + (long)i1 * 64 + quad * 8;
    dst[0][0] = *(const bf16x8*)(r0);
    dst[0][1] = *(const bf16x8*)(r0 + 32);
    dst[1][0] = *(const bf16x8*)(r1);
    dst[1][1] = *(const bf16x8*)(r1 + 32);
}

__device__ __forceinline__ void loadB(const unsigned short* __restrict__ wk,
                                      int m16, bf16x8 (&dst)[4][2]) {
    #pragma unroll
    for (int t = 0; t < 4; ++t)
        #pragma unroll
        for (int s = 0; s < 2; ++s)
            dst[t][s] = *(const bf16x8*)(wk + (t * 16 + m16) * 64 + s * 32);
}

// ---------------- map build: idxG[block][k][row&31], 32 k-slots x 32 rows = 4KB/block ----------------
__global__ void fill_i32(int* __restrict__ p, long tot, int val) {
    long i = (long)blockIdx.x * blockDim.x + threadIdx.x;
    if (i < tot) p[i] = val;
}

__global__ void invert_map_g(const int* __restrict__ km_in, const int* __restrict__ km_out,
                             int* __restrict__ idxG, int M, int nrows) {
    long i = (long)blockIdx.x * blockDim.x + threadIdx.x;
    if (i >= (long)KK * M) return;
    int k = (int)(i / M);
    int ki = km_in[i];
    if (ki < nrows) {
        int ko = km_out[i];
        idxG[(long)(ko >> 5) * 1024 + k * 32 + (ko & 31)] = ki;
    }
}

// ---------------- weight prep ----------------
__global__ void wt_bf16(const float* __restrict__ W, unsigned short* __restrict__ Wt,
                        int Cin, int Cout) {
    long i = (long)blockIdx.x * blockDim.x + threadIdx.x;
    long tot = (long)KK * Cin * Cout;
    if (i >= tot) return;
    int k  = (int)(i / (Cin * Cout));
    int r  = (int)(i % (Cin * Cout));
    int ci = r / Cout, co = r % Cout;
    Wt[((long)k * Cout + co) * Cin + ci] = f2bf(W[i]);
}

__global__ void w1t_bf16(const float* __restrict__ W1, unsigned short* __restrict__ W1t) {
    int i = blockIdx.x * blockDim.x + threadIdx.x;
    if (i >= 64 * 32) return;
    int c = i / 32, kk = i % 32;
    W1t[i] = (kk < KK) ? f2bf(W1[kk * 64 + c]) : (unsigned short)0;
}

// ---------------- conv1 gather-MFMA (1->64), fused stats ----------------
__global__ __launch_bounds__(256, 2) void conv1_mfma(const float* __restrict__ feats,
                                                     const unsigned short* __restrict__ W1t,
                                                     const int* __restrict__ idxG, int n,
                                                     unsigned short* __restrict__ out,
                                                     float* __restrict__ st) {
    int wave = threadIdx.x >> 6, lane = threadIdx.x & 63;
    int m16 = lane & 15, quad = lane >> 4;
    long tile = (long)blockIdx.x * 4 + wave;
    long j0 = tile * 32;
    if (j0 >= n) return;
    int jm[2] = {(int)j0 + m16, (int)j0 + 16 + m16};

    int idx[2][8];
    #pragma unroll
    for (int i = 0; i < 8; ++i) {
        int kk = quad * 8 + i;
        bool kv = (kk < KK);
        #pragma unroll
        for (int t2 = 0; t2 < 2; ++t2)
            idx[t2][i] = kv ? idxG[(long)(jm[t2] >> 5) * 1024 + kk * 32 + (jm[t2] & 31)] : n;
    }
    float f[2][8];
    #pragma unroll
    for (int i = 0; i < 8; ++i)
        #pragma unroll
        for (int t2 = 0; t2 < 2; ++t2) {
            int r = idx[t2][i];
            f[t2][i] = (r < n) ? feats[r] : 0.f;
        }

    union { bf16x8 v; unsigned short s[8]; } a[2];
    #pragma unroll
    for (int t2 = 0; t2 < 2; ++t2)
        #pragma unroll
        for (int i = 0; i < 8; ++i) a[t2].s[i] = f2bf(f[t2][i]);

    f32x4 acc[2][4];
    #pragma unroll
    for (int t2 = 0; t2 < 2; ++t2)
        #pragma unroll
        for (int t = 0; t < 4; ++t) acc[t2][t] = (f32x4){0.f, 0.f, 0.f, 0.f};

    const unsigned short* wb = W1t + quad * 8;
    #pragma unroll
    for (int t = 0; t < 4; ++t) {
        bf16x8 b = *(const bf16x8*)(wb + (t * 16 + m16) * 32);
        acc[0][t] = mfma16(a[0].v, b, acc[0][t]);
        acc[1][t] = mfma16(a[1].v, b, acc[1][t]);
    }

    #pragma unroll
    for (int t2 = 0; t2 < 2; ++t2) {
        long row = j0 + t2 * 16 + quad * 4;
        #pragma unroll
        for (int t = 0; t < 4; ++t)
            #pragma unroll
            for (int r2 = 0; r2 < 4; ++r2) {
                long rr = row + r2;
                if (rr < n) out[rr * 64 + t * 16 + m16] = f2bf(acc[t2][t][r2]);
            }
    }
    #pragma unroll
    for (int t = 0; t < 4; ++t) {
        float s = 0.f, q = 0.f;
        #pragma unroll
        for (int t2 = 0; t2 < 2; ++t2)
            #pragma unroll
            for (int r2 = 0; r2 < 4; ++r2) { float v = acc[t2][t][r2]; s += v; q += v * v; }
        s += __shfl_xor(s, 16); q += __shfl_xor(q, 16);
        s += __shfl_xor(s, 32); q += __shfl_xor(q, 32);
        if (quad == 0) {
            atomicAdd(&st[t * 16 + m16], s);
            atomicAdd(&st[64 + t * 16 + m16], q);
        }
    }
}

// ---------------- BN+ReLU in place on bf16, 8-wide ----------------
__global__ void bnrelu1_vec(unsigned short* __restrict__ x, const float* __restrict__ stats,
                            const float* __restrict__ g, const float* __restrict__ be, long n) {
    __shared__ float sc[64], sh[64];
    int tid = threadIdx.x;
    if (tid < 64) {
        float mu  = stats[tid] / (float)n;
        float var = stats[64 + tid] / (float)n - mu * mu;
        float s   = g[tid] * rsqrtf(var + EPS);
        sc[tid] = s; sh[tid] = be[tid] - mu * s;
    }
    __syncthreads();
    long i = (long)blockIdx.x * 256 + tid;
    long tot = (n + 1) * 8;
    if (i >= tot) return;
    long j = i >> 3; int c0 = (int)(i & 7) * 8;
    union { bf16x8 v; unsigned short s[8]; } u, o;
    if (j < n) {
        u.v = *(const bf16x8*)(x + j * 64 + c0);
        #pragma unroll
        for (int t = 0; t < 8; ++t) {
            float f = bf2f(u.s[t]) * sc[c0 + t] + sh[c0 + t];
            o.s[t] = f2bf(f > 0.f ? f : 0.f);
        }
    } else {
        #pragma unroll
        for (int t = 0; t < 8; ++t) o.s[t] = 0;
    }
    *(bf16x8*)(x + j * 64 + c0) = o.v;
}

// ---------------- MFMA gather-conv: LDS-idx + uniform-depth register pipeline ----------------
// Wave = 32 rows x 64 cols (colblk picks 64 of CB*64). idx: one 4KB coalesced
// global_load_lds stage, then 2 conflict-free ds_read_b32/iter (lgkm domain).
// VMEM streams uniform depth, issue order pinned: B(k+1) older than gather(k+2)
// -> binding wait is vmcnt(16), gathers keep 2-iter slack. A ring 3, B ring 2.
template <int CB, int MINW, bool BF16OUT>
__global__ __launch_bounds__(256, MINW) void conv_mfma(const unsigned short* __restrict__ xin,
                                                       const unsigned short* __restrict__ Wt,
                                                       const int* __restrict__ idxG,
                                                       void* __restrict__ outv, int n,
                                                       float* __restrict__ st) {
    constexpr int COUT = CB * 64;
    constexpr int NT = 4;
    __shared__ __align__(16) int lidx[4][1024];
    int wave = threadIdx.x >> 6, lane = threadIdx.x & 63;
    int m16 = lane & 15, quad = lane >> 4;

    long w = (long)blockIdx.x * 4 + wave;
    long tile = w / CB;
    int colblk = (int)(w % CB);
    long j0 = tile * 32;
    if (j0 >= n) return;

    // stage this tile's 27x32 idx block (4KB, coalesced, wave-uniform dest)
    {
        const int* src = idxG + (j0 >> 5) * 1024;
        #pragma unroll
        for (int i = 0; i < 4; ++i)
            __builtin_amdgcn_global_load_lds(
                (const __attribute__((address_space(1))) unsigned*)(src + i * 256 + lane * 4),
                (__attribute__((address_space(3))) unsigned*)(&lidx[wave][i * 256]),
                16, 0, 0);
        wait_vm0();
    }
    __builtin_amdgcn_sched_barrier(0);

    const int* ip = &lidx[wave][m16];   // row m16 at +0, row 16+m16 at +64B
    const unsigned short* wcol = Wt + (long)(colblk * 64) * 64 + quad * 8;

    int i0 = ip[0 * 32], i1 = ip[0 * 32 + 16];
    int p0 = ip[1 * 32], p1 = ip[1 * 32 + 16];

    bf16x8 ab[3][2][2];
    gatherA(xin, i0, i1, quad, ab[0]);
    gatherA(xin, p0, p1, quad, ab[1]);
    bf16x8 bb[2][NT][2];
    loadB(wcol, m16, bb[0]);
    __builtin_amdgcn_sched_barrier(0);

    f32x4 acc[2][NT];
    #pragma unroll
    for (int t2 = 0; t2 < 2; ++t2)
        #pragma unroll
        for (int t = 0; t < NT; ++t) acc[t2][t] = (f32x4){0.f, 0.f, 0.f, 0.f};

    #pragma unroll
    for (int k = 0; k < KK; ++k) {
        int n0 = 0, n1 = 0;
        if (k + 2 < KK) { n0 = ip[(k + 2) * 32]; n1 = ip[(k + 2) * 32 + 16]; }
        if (k + 1 < KK) loadB(wcol + (long)(k + 1) * (COUT * 64), m16, bb[(k + 1) & 1]);
        if (k + 2 < KK) gatherA(xin, n0, n1, quad, ab[(k + 2) % 3]);
        #pragma unroll
        for (int s = 0; s < 2; ++s)
            #pragma unroll
            for (int t = 0; t < NT; ++t) {
                acc[0][t] = mfma16(ab[k % 3][0][s], bb[k & 1][t][s], acc[0][t]);
                acc[1][t] = mfma16(ab[k % 3][1][s], bb[k & 1][t][s], acc[1][t]);
            }
        __builtin_amdgcn_sched_barrier(0);
    }

    #pragma unroll
    for (int t2 = 0; t2 < 2; ++t2) {
        long row = j0 + t2 * 16 + quad * 4;    // D: col=m16, row=quad*4+reg
        #pragma unroll
        for (int t = 0; t < NT; ++t)
            #pragma unroll
            for (int r2 = 0; r2 < 4; ++r2) {
                long rr = row + r2;
                if (rr < n) {
                    long o = rr * COUT + colblk * 64 + t * 16 + m16;
                    if (BF16OUT) ((unsigned short*)outv)[o] = f2bf(acc[t2][t][r2]);
                    else         ((float*)outv)[o] = acc[t2][t][r2];
                }
            }
    }
    #pragma unroll
    for (int t = 0; t < NT; ++t) {
        float s = 0.f, q = 0.f;
        #pragma unroll
        for (int t2 = 0; t2 < 2; ++t2)
            #pragma unroll
            for (int r2 = 0; r2 < 4; ++r2) { float v = acc[t2][t][r2]; s += v; q += v * v; }
        s += __shfl_xor(s, 16); q += __shfl_xor(q, 16);
        s += __shfl_xor(s, 32); q += __shfl_xor(q, 32);
        if (quad == 0) {
            atomicAdd(&st[colblk * 64 + t * 16 + m16], s);
            atomicAdd(&st[COUT + colblk * 64 + t * 16 + m16], q);
        }
    }
}

// ---------------- BN+ReLU on bf16 x2 fused with segment-max pool ----------------
__global__ void pool_kernel(const unsigned short* __restrict__ x, const float* __restrict__ stats,
                            const float* __restrict__ g, const float* __restrict__ be,
                            const int* __restrict__ seg, long n, unsigned* __restrict__ pooled) {
    long j = (long)blockIdx.x * 4 + threadIdx.y;
    if (j >= n) return;
    int c = threadIdx.x;
    float mu  = stats[c] / (float)n;
    float var = stats[64 + c] / (float)n - mu * mu;
    float rs  = rsqrtf(var + EPS);
    float v   = g[c] * (bf2f(x[j * 64 + c]) - mu) * rs + be[c];
    if (v < 0.f) v = 0.f;
    atomicMax(&pooled[(long)seg[j] * 64 + c], __float_as_uint(v));
}

__global__ void pooled_bf16_vec(const unsigned* __restrict__ pooled, long np,
                                unsigned short* __restrict__ out) {
    long i = (long)blockIdx.x * 256 + threadIdx.x;
    long tot = (np + 1) * 8;
    if (i >= tot) return;
    long j = i >> 3; int c0 = (int)(i & 7) * 8;
    union { bf16x8 v; unsigned short s[8]; } o;
    if (j < np) {
        #pragma unroll
        for (int t = 0; t < 8; ++t)
            o.s[t] = f2bf(__uint_as_float(pooled[j * 64 + c0 + t]));
    } else {
        #pragma unroll
        for (int t = 0; t < 8; ++t) o.s[t] = 0;
    }
    *(bf16x8*)(out + j * 64 + c0) = o.v;
}

// ---------------- final BN+ReLU in place on d_out, float4 ----------------
__global__ void bnrelu_out_vec(float* __restrict__ x, const float* __restrict__ stats,
                               const float* __restrict__ g, const float* __restrict__ be,
                               long n) {
    __shared__ float sc[128], sh[128];
    int tid = threadIdx.x;
    if (tid < 128) {
        float mu  = stats[tid] / (float)n;
        float var = stats[128 + tid] / (float)n - mu * mu;
        float s   = g[tid] * rsqrtf(var + EPS);
        sc[tid] = s; sh[tid] = be[tid] - mu * s;
    }
    __syncthreads();
    long i = (long)blockIdx.x * 256 + tid;
    long tot = n * 32;
    if (i >= tot) return;
    int c0 = (int)(i & 31) * 4;
    float4 v = ((float4*)x)[i];
    v.x = v.x * sc[c0]     + sh[c0];     v.x = v.x > 0.f ? v.x : 0.f;
    v.y = v.y * sc[c0 + 1] + sh[c0 + 1]; v.y = v.y > 0.f ? v.y : 0.f;
    v.z = v.z * sc[c0 + 2] + sh[c0 + 2]; v.z = v.z > 0.f ? v.z : 0.f;
    v.w = v.w * sc[c0 + 3] + sh[c0 + 3]; v.w = v.w > 0.f ? v.w : 0.f;
    ((float4*)x)[i] = v;
}

extern "C" void kernel_launch(void* const* d_in, const int* in_sizes, int n_in,
                              void* d_out, int out_size, void* d_ws, size_t ws_size,
                              hipStream_t stream) {
    const float* feats = (const float*)d_in[0];
    const float* W1  = (const float*)d_in[1];
    const float* g1  = (const float*)d_in[3];
    const float* be1 = (const float*)d_in[4];
    const float* W2  = (const float*)d_in[5];
    const float* g2  = (const float*)d_in[7];
    const float* be2 = (const float*)d_in[8];
    const float* W3  = (const float*)d_in[9];
    const float* g3  = (const float*)d_in[11];
    const float* be3 = (const float*)d_in[12];
    const int* km_in   = (const int*)d_in[13];
    const int* km_out  = (const int*)d_in[14];
    const int* pool_seg = (const int*)d_in[15];
    const int* km2_in  = (const int*)d_in[16];
    const int* km2_out = (const int*)d_in[17];

    const int n  = in_sizes[0];           // 160000
    const int M  = in_sizes[13] / KK;
    const int np = out_size / 128;        // N_POOL
    const int M2 = in_sizes[16] / KK;
    const long nb1 = n / 32 + 2;          // idx blocks (32 rows, 4KB each)
    const long nb2 = np / 32 + 2;

    // bias terms (b1/b2/b3) skipped: constant per-channel shift cancels through
    // training-mode BatchNorm exactly (mean-subtracted, variance unchanged).

    char* ws = (char*)d_ws;
    size_t off = 0;
    auto alloc = [&](size_t bytes) -> char* {
        char* p = ws + off;
        off += (bytes + 255) & ~(size_t)255;
        return p;
    };
    int* idxG1 = (int*)alloc(nb1 * 4096);
    int* idxG2 = (int*)alloc(nb2 * 4096);
    unsigned short* W1t = (unsigned short*)alloc(64 * 32 * 2);
    unsigned short* W2t = (unsigned short*)alloc((size_t)KK * 64 * 64 * 2);
    unsigned short* W3t = (unsigned short*)alloc((size_t)KK * 128 * 64 * 2);
    float* stats = (float*)alloc(4096);
    unsigned short* x1n = (unsigned short*)alloc((size_t)(n + 1) * 64 * 2);
    unsigned short* x2r = (unsigned short*)alloc((size_t)n * 64 * 2);
    unsigned* pooled = (unsigned*)alloc((size_t)np * 64 * 4);
    unsigned short* xpn = (unsigned short*)alloc((size_t)(np + 1) * 64 * 2);
    float* x3 = (float*)d_out;
    if (off > ws_size) return;

    float* stats1 = stats;
    float* stats2 = stats + 128;
    float* stats3 = stats + 256;

    hipMemsetAsync(stats, 0, 4096, stream);
    hipMemsetAsync(pooled, 0, (size_t)np * 64 * 4, stream);

    {
        long t1 = nb1 * 1024;
        fill_i32<<<(int)((t1 + 255) / 256), 256, 0, stream>>>(idxG1, t1, n);
        long t2 = nb2 * 1024;
        fill_i32<<<(int)((t2 + 255) / 256), 256, 0, stream>>>(idxG2, t2, np);
        long e1 = (long)KK * M;
        invert_map_g<<<(int)((e1 + 255) / 256), 256, 0, stream>>>(km_in, km_out, idxG1, M, n);
        long e2 = (long)KK * M2;
        invert_map_g<<<(int)((e2 + 255) / 256), 256, 0, stream>>>(km2_in, km2_out, idxG2, M2, np);
    }
    {
        w1t_bf16<<<8, 256, 0, stream>>>(W1, W1t);
        long t2 = (long)KK * 64 * 64;
        wt_bf16<<<(int)((t2 + 255) / 256), 256, 0, stream>>>(W2, W2t, 64, 64);
        long t3 = (long)KK * 64 * 128;
        wt_bf16<<<(int)((t3 + 255) / 256), 256, 0, stream>>>(W3, W3t, 64, 128);
    }

    // layer 1 (+stats1 fused)
    {
        long waves = (n + 31) / 32;
        conv1_mfma<<<(int)((waves + 3) / 4), 256, 0, stream>>>(feats, W1t, idxG1, n, x1n, stats1);
    }
    {
        long tot = ((long)(n + 1) * 8 + 255) / 256;
        bnrelu1_vec<<<(int)tot, 256, 0, stream>>>(x1n, stats1, g1, be1, n);
    }
    // layer 2 (+stats2 fused): CB=1, 64 cols
    {
        long waves = (n + 31) / 32;
        conv_mfma<1, 3, true><<<(int)((waves + 3) / 4), 256, 0, stream>>>(x1n, W2t, idxG1, x2r, n, stats2);
    }
    pool_kernel<<<(n + 3) / 4, dim3(64, 4), 0, stream>>>(x2r, stats2, g2, be2, pool_seg, n, pooled);
    {
        long tot = ((long)(np + 1) * 8 + 255) / 256;
        pooled_bf16_vec<<<(int)tot, 256, 0, stream>>>(pooled, np, xpn);
    }
    // layer 3 (+stats3 fused): CB=2 column split, 2x64 cols
    {
        long waves = ((long)(np + 31) / 32) * 2;
        conv_mfma<2, 3, false><<<(int)((waves + 3) / 4), 256, 0, stream>>>(xpn, W3t, idxG2, x3, np, stats3);
    }
    {
        long tot = ((long)np * 32 + 255) / 256;
        bnrelu_out_vec<<<(int)tot, 256, 0, stream>>>(x3, stats3, g3, be3, np);
    }
}

// Round 9
// 589.844 us; speedup vs baseline: 1.2009x; 1.2009x over previous
//
#include <hip/hip_runtime.h>

#define EPS 1e-5f
#define KK 27

typedef __bf16 bf16x8 __attribute__((ext_vector_type(8)));
typedef float f32x4 __attribute__((ext_vector_type(4)));

__device__ __forceinline__ unsigned short f2bf(float f) {
    union { float f; unsigned u; } v; v.f = f;
    unsigned r = v.u + 0x7fffu + ((v.u >> 16) & 1u);  // round-to-nearest-even
    return (unsigned short)(r >> 16);
}
__device__ __forceinline__ float bf2f(unsigned short h) {
    union { unsigned u; float f; } v; v.u = ((unsigned)h) << 16; return v.f;
}

__device__ __forceinline__ f32x4 mfma16(bf16x8 a, bf16x8 b, f32x4 c) {
    return __builtin_amdgcn_mfma_f32_16x16x32_bf16(a, b, c, 0, 0, 0);
}

// ---------------- map build: idxG[block][k][row&31] ----------------
__global__ void fill_i32(int* __restrict__ p, long tot, int val) {
    long i = (long)blockIdx.x * blockDim.x + threadIdx.x;
    if (i < tot) p[i] = val;
}

__global__ void invert_map_g(const int* __restrict__ km_in, const int* __restrict__ km_out,
                             int* __restrict__ idxG, int M, int nrows) {
    long i = (long)blockIdx.x * blockDim.x + threadIdx.x;
    if (i >= (long)KK * M) return;
    int k = (int)(i / M);
    int ki = km_in[i];
    if (ki < nrows) {
        int ko = km_out[i];
        idxG[(long)(ko >> 5) * 1024 + k * 32 + (ko & 31)] = ki;
    }
}

// ---------------- weight prep ----------------
// W[k][ci][co] f32 -> fragment-major bf16 halves:
// off = (((k*(Cout/16) + t)*2 + s)*64 + lane)*8 + j
// where co = t*16+m16, ci = s*32+quad*8+j, lane = quad*16+m16.
// K-slice is then linear; a lane's B-frag (t,s) is 16B at ((t*2+s)*64+lane)*16.
__global__ void wt_frag(const float* __restrict__ W, unsigned short* __restrict__ Wt,
                        int Cin, int Cout) {
    long i = (long)blockIdx.x * blockDim.x + threadIdx.x;
    long tot = (long)KK * Cin * Cout;
    if (i >= tot) return;
    int k  = (int)(i / (Cin * Cout));
    int r  = (int)(i % (Cin * Cout));
    int ci = r / Cout, co = r % Cout;
    int t = co >> 4, m16 = co & 15;
    int s = ci >> 5, quad = (ci >> 3) & 3, j = ci & 7;
    int lane = quad * 16 + m16;
    long off = ((((long)k * (Cout >> 4) + t) * 2 + s) * 64 + lane) * 8 + j;
    Wt[off] = f2bf(W[i]);
}

__global__ void w1t_bf16(const float* __restrict__ W1, unsigned short* __restrict__ W1t) {
    int i = blockIdx.x * blockDim.x + threadIdx.x;
    if (i >= 64 * 32) return;
    int c = i / 32, kk = i % 32;
    W1t[i] = (kk < KK) ? f2bf(W1[kk * 64 + c]) : (unsigned short)0;
}

// ---------------- conv1 gather-MFMA (1->64), fused stats ----------------
__global__ __launch_bounds__(256, 2) void conv1_mfma(const float* __restrict__ feats,
                                                     const unsigned short* __restrict__ W1t,
                                                     const int* __restrict__ idxG, int n,
                                                     unsigned short* __restrict__ out,
                                                     float* __restrict__ st) {
    int wave = threadIdx.x >> 6, lane = threadIdx.x & 63;
    int m16 = lane & 15, quad = lane >> 4;
    long tile = (long)blockIdx.x * 4 + wave;
    long j0 = tile * 32;
    if (j0 >= n) return;
    int jm[2] = {(int)j0 + m16, (int)j0 + 16 + m16};

    int idx[2][8];
    #pragma unroll
    for (int i = 0; i < 8; ++i) {
        int kk = quad * 8 + i;
        bool kv = (kk < KK);
        #pragma unroll
        for (int t2 = 0; t2 < 2; ++t2)
            idx[t2][i] = kv ? idxG[(long)(jm[t2] >> 5) * 1024 + kk * 32 + (jm[t2] & 31)] : n;
    }
    float f[2][8];
    #pragma unroll
    for (int i = 0; i < 8; ++i)
        #pragma unroll
        for (int t2 = 0; t2 < 2; ++t2) {
            int r = idx[t2][i];
            f[t2][i] = (r < n) ? feats[r] : 0.f;
        }

    union { bf16x8 v; unsigned short s[8]; } a[2];
    #pragma unroll
    for (int t2 = 0; t2 < 2; ++t2)
        #pragma unroll
        for (int i = 0; i < 8; ++i) a[t2].s[i] = f2bf(f[t2][i]);

    f32x4 acc[2][4];
    #pragma unroll
    for (int t2 = 0; t2 < 2; ++t2)
        #pragma unroll
        for (int t = 0; t < 4; ++t) acc[t2][t] = (f32x4){0.f, 0.f, 0.f, 0.f};

    const unsigned short* wb = W1t + quad * 8;
    #pragma unroll
    for (int t = 0; t < 4; ++t) {
        bf16x8 b = *(const bf16x8*)(wb + (t * 16 + m16) * 32);
        acc[0][t] = mfma16(a[0].v, b, acc[0][t]);
        acc[1][t] = mfma16(a[1].v, b, acc[1][t]);
    }

    #pragma unroll
    for (int t2 = 0; t2 < 2; ++t2) {
        long row = j0 + t2 * 16 + quad * 4;
        #pragma unroll
        for (int t = 0; t < 4; ++t)
            #pragma unroll
            for (int r2 = 0; r2 < 4; ++r2) {
                long rr = row + r2;
                if (rr < n) out[rr * 64 + t * 16 + m16] = f2bf(acc[t2][t][r2]);
            }
    }
    #pragma unroll
    for (int t = 0; t < 4; ++t) {
        float s = 0.f, q = 0.f;
        #pragma unroll
        for (int t2 = 0; t2 < 2; ++t2)
            #pragma unroll
            for (int r2 = 0; r2 < 4; ++r2) { float v = acc[t2][t][r2]; s += v; q += v * v; }
        s += __shfl_xor(s, 16); q += __shfl_xor(q, 16);
        s += __shfl_xor(s, 32); q += __shfl_xor(q, 32);
        if (quad == 0) {
            atomicAdd(&st[t * 16 + m16], s);
            atomicAdd(&st[64 + t * 16 + m16], q);
        }
    }
}

// ---------------- BN+ReLU in place on bf16, 8-wide ----------------
__global__ void bnrelu1_vec(unsigned short* __restrict__ x, const float* __restrict__ stats,
                            const float* __restrict__ g, const float* __restrict__ be, long n) {
    __shared__ float sc[64], sh[64];
    int tid = threadIdx.x;
    if (tid < 64) {
        float mu  = stats[tid] / (float)n;
        float var = stats[64 + tid] / (float)n - mu * mu;
        float s   = g[tid] * rsqrtf(var + EPS);
        sc[tid] = s; sh[tid] = be[tid] - mu * s;
    }
    __syncthreads();
    long i = (long)blockIdx.x * 256 + tid;
    long tot = (n + 1) * 8;
    if (i >= tot) return;
    long j = i >> 3; int c0 = (int)(i & 7) * 8;
    union { bf16x8 v; unsigned short s[8]; } u, o;
    if (j < n) {
        u.v = *(const bf16x8*)(x + j * 64 + c0);
        #pragma unroll
        for (int t = 0; t < 8; ++t) {
            float f = bf2f(u.s[t]) * sc[c0 + t] + sh[c0 + t];
            o.s[t] = f2bf(f > 0.f ? f : 0.f);
        }
    } else {
        #pragma unroll
        for (int t = 0; t < 8; ++t) o.s[t] = 0;
    }
    *(bf16x8*)(x + j * 64 + c0) = o.v;
}

// ---------------- MFMA gather-conv: B in LDS (double-buffered), A prefetch+1 ----------------
// Wave = 32 rows x COUT cols; block = 4 waves = 128 rows sharing the B tile.
// B: cooperative global_load_lds into 2-slot LDS ring, 1 barrier/iter; read back
// via broadcast ds_read_b128 (lgkm domain -> out of the vmcnt picture).
// A: the only K-loop VMEM; issued for k+1 before the barrier, whose mandatory
// vmcnt(0) drain doubles as the prefetch wait. No manual waitcnt, no big rings.
template <int NT, bool BF16OUT>
__global__ __launch_bounds__(256, 2) void conv_mfma(const unsigned short* __restrict__ xin,
                                                    const unsigned short* __restrict__ Wt,
                                                    const int* __restrict__ idxG,
                                                    void* __restrict__ outv, int n,
                                                    float* __restrict__ st) {
    constexpr int COUT = NT * 16;
    constexpr int SLICE = COUT * 64 * 2;        // bytes per k-slice
    constexpr int ROUNDS = SLICE / 4096;        // 256 thr x 16B per round
    __shared__ __align__(16) int lidx[4][1024];
    __shared__ __align__(16) char bbuf[2][SLICE];

    int tid = threadIdx.x;
    int wave = tid >> 6, lane = tid & 63;
    int m16 = lane & 15, quad = lane >> 4;
    long tile = (long)blockIdx.x * 4 + wave;
    long j0 = tile * 32;
    bool valid = (j0 < n);
    long jb = valid ? (j0 >> 5) : 0;

    // stage this wave's 27x32 idx block (4KB, coalesced)
    {
        const int* src = idxG + jb * 1024;
        #pragma unroll
        for (int i = 0; i < 4; ++i)
            __builtin_amdgcn_global_load_lds(
                (const __attribute__((address_space(1))) unsigned*)(src + i * 256 + lane * 4),
                (__attribute__((address_space(3))) unsigned*)(&lidx[wave][i * 256]),
                16, 0, 0);
    }
    // stage B[0]
    {
        const char* src = (const char*)Wt;
        #pragma unroll
        for (int r = 0; r < ROUNDS; ++r)
            __builtin_amdgcn_global_load_lds(
                (const __attribute__((address_space(1))) unsigned*)(src + r * 4096 + wave * 1024 + lane * 16),
                (__attribute__((address_space(3))) unsigned*)(&bbuf[0][r * 4096 + wave * 1024]),
                16, 0, 0);
    }
    __syncthreads();   // idx + B[0] resident

    const int* lip = &lidx[wave][m16];
    bf16x8 ab[2][2][2];   // [ring][t2][s]
    {
        int r0 = valid ? lip[0] : n, r1 = valid ? lip[16] : n;
        const unsigned short* a0 = xin + (long)r0 * 64 + quad * 8;
        const unsigned short* a1 = xin + (long)r1 * 64 + quad * 8;
        ab[0][0][0] = *(const bf16x8*)a0;
        ab[0][0][1] = *(const bf16x8*)(a0 + 32);
        ab[0][1][0] = *(const bf16x8*)a1;
        ab[0][1][1] = *(const bf16x8*)(a1 + 32);
    }

    f32x4 acc[2][NT];
    #pragma unroll
    for (int t2 = 0; t2 < 2; ++t2)
        #pragma unroll
        for (int t = 0; t < NT; ++t) acc[t2][t] = (f32x4){0.f, 0.f, 0.f, 0.f};

    #pragma unroll
    for (int k = 0; k < KK; ++k) {
        const int kb = k & 1;
        if (k + 1 < KK) {
            // stage B[k+1] into the other slot (its consumers synced last barrier)
            const char* src = (const char*)Wt + (long)(k + 1) * SLICE;
            #pragma unroll
            for (int r = 0; r < ROUNDS; ++r)
                __builtin_amdgcn_global_load_lds(
                    (const __attribute__((address_space(1))) unsigned*)(src + r * 4096 + wave * 1024 + lane * 16),
                    (__attribute__((address_space(3))) unsigned*)(&bbuf[1 - kb][r * 4096 + wave * 1024]),
                    16, 0, 0);
            // A for k+1 (prefetch: drained by the barrier's vmcnt(0))
            int r0 = valid ? lip[(k + 1) * 32] : n;
            int r1 = valid ? lip[(k + 1) * 32 + 16] : n;
            const unsigned short* a0 = xin + (long)r0 * 64 + quad * 8;
            const unsigned short* a1 = xin + (long)r1 * 64 + quad * 8;
            ab[1 - kb][0][0] = *(const bf16x8*)a0;
            ab[1 - kb][0][1] = *(const bf16x8*)(a0 + 32);
            ab[1 - kb][1][0] = *(const bf16x8*)a1;
            ab[1 - kb][1][1] = *(const bf16x8*)(a1 + 32);
        }
        // consume B[k] (LDS broadcast) x A[k]
        #pragma unroll
        for (int s = 0; s < 2; ++s)
            #pragma unroll
            for (int t = 0; t < NT; ++t) {
                bf16x8 b = *(const bf16x8*)&bbuf[kb][((t * 2 + s) * 64 + lane) * 16];
                acc[0][t] = mfma16(ab[kb][0][s], b, acc[0][t]);
                acc[1][t] = mfma16(ab[kb][1][s], b, acc[1][t]);
            }
        if (k + 1 < KK) __syncthreads();
    }

    if (valid) {
        #pragma unroll
        for (int t2 = 0; t2 < 2; ++t2) {
            long row = j0 + t2 * 16 + quad * 4;    // D: col=m16, row=quad*4+reg
            #pragma unroll
            for (int t = 0; t < NT; ++t)
                #pragma unroll
                for (int r2 = 0; r2 < 4; ++r2) {
                    long rr = row + r2;
                    if (rr < n) {
                        long o = rr * COUT + t * 16 + m16;
                        if (BF16OUT) ((unsigned short*)outv)[o] = f2bf(acc[t2][t][r2]);
                        else         ((float*)outv)[o] = acc[t2][t][r2];
                    }
                }
        }
        #pragma unroll
        for (int t = 0; t < NT; ++t) {
            float s = 0.f, q = 0.f;
            #pragma unroll
            for (int t2 = 0; t2 < 2; ++t2)
                #pragma unroll
                for (int r2 = 0; r2 < 4; ++r2) { float v = acc[t2][t][r2]; s += v; q += v * v; }
            s += __shfl_xor(s, 16); q += __shfl_xor(q, 16);
            s += __shfl_xor(s, 32); q += __shfl_xor(q, 32);
            if (quad == 0) {
                atomicAdd(&st[t * 16 + m16], s);
                atomicAdd(&st[COUT + t * 16 + m16], q);
            }
        }
    }
}

// ---------------- BN+ReLU on bf16 x2 fused with segment-max pool ----------------
__global__ void pool_kernel(const unsigned short* __restrict__ x, const float* __restrict__ stats,
                            const float* __restrict__ g, const float* __restrict__ be,
                            const int* __restrict__ seg, long n, unsigned* __restrict__ pooled) {
    long j = (long)blockIdx.x * 4 + threadIdx.y;
    if (j >= n) return;
    int c = threadIdx.x;
    float mu  = stats[c] / (float)n;
    float var = stats[64 + c] / (float)n - mu * mu;
    float rs  = rsqrtf(var + EPS);
    float v   = g[c] * (bf2f(x[j * 64 + c]) - mu) * rs + be[c];
    if (v < 0.f) v = 0.f;
    atomicMax(&pooled[(long)seg[j] * 64 + c], __float_as_uint(v));
}

__global__ void pooled_bf16_vec(const unsigned* __restrict__ pooled, long np,
                                unsigned short* __restrict__ out) {
    long i = (long)blockIdx.x * 256 + threadIdx.x;
    long tot = (np + 1) * 8;
    if (i >= tot) return;
    long j = i >> 3; int c0 = (int)(i & 7) * 8;
    union { bf16x8 v; unsigned short s[8]; } o;
    if (j < np) {
        #pragma unroll
        for (int t = 0; t < 8; ++t)
            o.s[t] = f2bf(__uint_as_float(pooled[j * 64 + c0 + t]));
    } else {
        #pragma unroll
        for (int t = 0; t < 8; ++t) o.s[t] = 0;
    }
    *(bf16x8*)(out + j * 64 + c0) = o.v;
}

// ---------------- final BN+ReLU in place on d_out, float4 ----------------
__global__ void bnrelu_out_vec(float* __restrict__ x, const float* __restrict__ stats,
                               const float* __restrict__ g, const float* __restrict__ be,
                               long n) {
    __shared__ float sc[128], sh[128];
    int tid = threadIdx.x;
    if (tid < 128) {
        float mu  = stats[tid] / (float)n;
        float var = stats[128 + tid] / (float)n - mu * mu;
        float s   = g[tid] * rsqrtf(var + EPS);
        sc[tid] = s; sh[tid] = be[tid] - mu * s;
    }
    __syncthreads();
    long i = (long)blockIdx.x * 256 + tid;
    long tot = n * 32;
    if (i >= tot) return;
    int c0 = (int)(i & 31) * 4;
    float4 v = ((float4*)x)[i];
    v.x = v.x * sc[c0]     + sh[c0];     v.x = v.x > 0.f ? v.x : 0.f;
    v.y = v.y * sc[c0 + 1] + sh[c0 + 1]; v.y = v.y > 0.f ? v.y : 0.f;
    v.z = v.z * sc[c0 + 2] + sh[c0 + 2]; v.z = v.z > 0.f ? v.z : 0.f;
    v.w = v.w * sc[c0 + 3] + sh[c0 + 3]; v.w = v.w > 0.f ? v.w : 0.f;
    ((float4*)x)[i] = v;
}

extern "C" void kernel_launch(void* const* d_in, const int* in_sizes, int n_in,
                              void* d_out, int out_size, void* d_ws, size_t ws_size,
                              hipStream_t stream) {
    const float* feats = (const float*)d_in[0];
    const float* W1  = (const float*)d_in[1];
    const float* g1  = (const float*)d_in[3];
    const float* be1 = (const float*)d_in[4];
    const float* W2  = (const float*)d_in[5];
    const float* g2  = (const float*)d_in[7];
    const float* be2 = (const float*)d_in[8];
    const float* W3  = (const float*)d_in[9];
    const float* g3  = (const float*)d_in[11];
    const float* be3 = (const float*)d_in[12];
    const int* km_in   = (const int*)d_in[13];
    const int* km_out  = (const int*)d_in[14];
    const int* pool_seg = (const int*)d_in[15];
    const int* km2_in  = (const int*)d_in[16];
    const int* km2_out = (const int*)d_in[17];

    const int n  = in_sizes[0];           // 160000
    const int M  = in_sizes[13] / KK;
    const int np = out_size / 128;        // N_POOL
    const int M2 = in_sizes[16] / KK;
    const long nb1 = n / 32 + 2;
    const long nb2 = np / 32 + 2;

    // bias terms (b1/b2/b3) skipped: constant per-channel shift cancels through
    // training-mode BatchNorm exactly (mean-subtracted, variance unchanged).

    char* ws = (char*)d_ws;
    size_t off = 0;
    auto alloc = [&](size_t bytes) -> char* {
        char* p = ws + off;
        off += (bytes + 255) & ~(size_t)255;
        return p;
    };
    int* idxG1 = (int*)alloc(nb1 * 4096);
    int* idxG2 = (int*)alloc(nb2 * 4096);
    unsigned short* W1t = (unsigned short*)alloc(64 * 32 * 2);
    unsigned short* W2t = (unsigned short*)alloc((size_t)KK * 64 * 64 * 2);
    unsigned short* W3t = (unsigned short*)alloc((size_t)KK * 128 * 64 * 2);
    float* stats = (float*)alloc(4096);
    unsigned short* x1n = (unsigned short*)alloc((size_t)(n + 1) * 64 * 2);
    unsigned short* x2r = (unsigned short*)alloc((size_t)n * 64 * 2);
    unsigned* pooled = (unsigned*)alloc((size_t)np * 64 * 4);
    unsigned short* xpn = (unsigned short*)alloc((size_t)(np + 1) * 64 * 2);
    float* x3 = (float*)d_out;
    if (off > ws_size) return;

    float* stats1 = stats;
    float* stats2 = stats + 128;
    float* stats3 = stats + 256;

    hipMemsetAsync(stats, 0, 4096, stream);
    hipMemsetAsync(pooled, 0, (size_t)np * 64 * 4, stream);

    {
        long t1 = nb1 * 1024;
        fill_i32<<<(int)((t1 + 255) / 256), 256, 0, stream>>>(idxG1, t1, n);
        long t2 = nb2 * 1024;
        fill_i32<<<(int)((t2 + 255) / 256), 256, 0, stream>>>(idxG2, t2, np);
        long e1 = (long)KK * M;
        invert_map_g<<<(int)((e1 + 255) / 256), 256, 0, stream>>>(km_in, km_out, idxG1, M, n);
        long e2 = (long)KK * M2;
        invert_map_g<<<(int)((e2 + 255) / 256), 256, 0, stream>>>(km2_in, km2_out, idxG2, M2, np);
    }
    {
        w1t_bf16<<<8, 256, 0, stream>>>(W1, W1t);
        long t2 = (long)KK * 64 * 64;
        wt_frag<<<(int)((t2 + 255) / 256), 256, 0, stream>>>(W2, W2t, 64, 64);
        long t3 = (long)KK * 64 * 128;
        wt_frag<<<(int)((t3 + 255) / 256), 256, 0, stream>>>(W3, W3t, 64, 128);
    }

    // layer 1 (+stats1 fused)
    {
        long waves = (n + 31) / 32;
        conv1_mfma<<<(int)((waves + 3) / 4), 256, 0, stream>>>(feats, W1t, idxG1, n, x1n, stats1);
    }
    {
        long tot = ((long)(n + 1) * 8 + 255) / 256;
        bnrelu1_vec<<<(int)tot, 256, 0, stream>>>(x1n, stats1, g1, be1, n);
    }
    // layer 2 (+stats2 fused): 64 cols
    {
        long waves = (n + 31) / 32;
        conv_mfma<4, true><<<(int)((waves + 3) / 4), 256, 0, stream>>>(x1n, W2t, idxG1, x2r, n, stats2);
    }
    pool_kernel<<<(n + 3) / 4, dim3(64, 4), 0, stream>>>(x2r, stats2, g2, be2, pool_seg, n, pooled);
    {
        long tot = ((long)(np + 1) * 8 + 255) / 256;
        pooled_bf16_vec<<<(int)tot, 256, 0, stream>>>(pooled, np, xpn);
    }
    // layer 3 (+stats3 fused): all 128 cols per wave
    {
        long waves = (np + 31) / 32;
        conv_mfma<8, false><<<(int)((waves + 3) / 4), 256, 0, stream>>>(xpn, W3t, idxG2, x3, np, stats3);
    }
    {
        long tot = ((long)np * 32 + 255) / 256;
        bnrelu_out_vec<<<(int)tot, 256, 0, stream>>>(x3, stats3, g3, be3, np);
    }
}